// Round 3
// baseline (7319.160 us; speedup 1.0000x reference)
//
#include <hip/hip_runtime.h>

#define Tn 512
#define In 40
#define Hn 256
#define Kn 4
#define On 16
#define ROWS 16                 // batch rows per block
#define NBLK 64                 // 1024 / ROWS

typedef _Float16 half8  __attribute__((ext_vector_type(8)));
typedef _Float16 half2v __attribute__((ext_vector_type(2)));
typedef float    f32x4  __attribute__((ext_vector_type(4)));

union U4H8 { uint4 u; half8 h; half2v h2[4]; };

static __device__ __forceinline__ half8 u2h(uint4 u) { U4H8 c; c.u = u; return c.h; }

static __device__ __forceinline__ float tanh_fast(float x) {
    float e = __expf(2.f * x);
    return 1.f - 2.f * __builtin_amdgcn_rcpf(e + 1.f);
}

// ---------------------------------------------------------------------------
// Weight pack: 640 fragments, frag f = w*80 + s*8 + t  (w=wave, s=slice, t=tile)
//   slice s<2  : input-proj K-slices (k = s*32.., padded 40->64 with zeros)
//   slice s>=2 : recurrent K-slices  (j = (s-2)*32..)
// Fragment = MFMA B operand [K=32 x N=16] fp16: lane l holds
//   B[k = (l>>4)*8 + j][n = l&15]  = W[out_col = base_n + (l&15)][k]
// stored as 8 contiguous fp16 (16B) at WPB[(f*64 + l)*8].
// ---------------------------------------------------------------------------
__global__ void pack_frags(const float* __restrict__ Wr, const float* __restrict__ Wi,
                           _Float16* __restrict__ WPB) {
    const int f = blockIdx.x;          // 0..639
    const int l = threadIdx.x;         // 0..63
    const int w = f / 80;
    const int rem = f - w * 80;
    const int s = rem >> 3, t = rem & 7;
    const int n = w * 128 + t * 16 + (l & 15);   // global output col 0..1023
    const int kloc = (l >> 4) * 8;
    half8 v;
    if (s < 2) {
#pragma unroll
        for (int j = 0; j < 8; j++) {
            const int k = s * 32 + kloc + j;
            v[j] = (k < In) ? (_Float16)Wi[n * In + k] : (_Float16)0.f;
        }
    } else {
#pragma unroll
        for (int j = 0; j < 8; j++)
            v[j] = (_Float16)Wr[(size_t)n * Hn + (s - 2) * 32 + kloc + j];
    }
    *(half8*)(WPB + ((size_t)f * 64 + l) * 8) = v;
}

// ---------------------------------------------------------------------------
// Main: 64 blocks x 512 threads (8 waves). Wave w owns output cols
// [w*128, w*128+128) = 8 MFMA tiles. LDS tiles XOR-swizzled: logical 16B slot
// S of row r lives at physical slot S ^ (r&7)  (G4 bank-conflict fix).
// ---------------------------------------------------------------------------
__global__ __launch_bounds__(512, 2) void diru_mfma(
    const float* __restrict__ x,
    const _Float16* __restrict__ WPB,
    const float* __restrict__ b_in, const float* __restrict__ b_rec,
    const float* __restrict__ W_gate, const float* __restrict__ b_gate,
    const float* __restrict__ W_fc, const float* __restrict__ b_fc,
    float* __restrict__ out)
{
    const int tid = threadIdx.x;
    const int l   = tid & 63;
    const int w   = tid >> 6;         // wave 0..7
    const int lm  = l & 15;           // A-row / B-col within tile
    const int lq  = l >> 4;           // k-quad 0..3
    const int b0  = blockIdx.x * ROWS;

    __shared__ _Float16 hh[ROWS * 256];     // h_t fp16, rows 512B, swizzled
    __shared__ _Float16 xs[ROWS * 64];      // x_t fp16 (pad 40->64), rows 128B, swizzled
    __shared__ _Float16 outs[ROWS * 1024];  // tanh outs, rows 2048B, swizzled
    __shared__ float    red[8 * ROWS * 4];  // gate partials [w][r][kg]

    // --- init: gate B-fragments (resident), biases ---
    half8 gb[4];
#pragma unroll
    for (int s2 = 0; s2 < 4; s2++) {
        half8 g = {};
        if (lm < Kn) {
#pragma unroll
            for (int j = 0; j < 8; j++)
                g[j] = (_Float16)W_gate[lm * 1024 + w * 128 + s2 * 32 + lq * 8 + j];
        }
        gb[s2] = g;
    }
    float bias[8];
#pragma unroll
    for (int t8 = 0; t8 < 8; t8++) {
        const int n = w * 128 + t8 * 16 + lm;
        bias[t8] = b_in[n] + b_rec[n];
    }
    float bg4[4];
#pragma unroll
    for (int kg = 0; kg < 4; kg++) bg4[kg] = b_gate[kg];

    // zero hh and xs (pad slots stay zero forever)
    for (int i = tid; i < ROWS * 256; i += 512) hh[i] = (_Float16)0.f;
    for (int i = tid; i < ROWS * 64;  i += 512) xs[i] = (_Float16)0.f;

    // x staging map (loop-invariant)
    const int xi0_r = tid / In, xi0_i = tid - xi0_r * In;
    const int has2  = (tid + 512) < ROWS * In;            // tid < 128
    const int t1    = tid + 512;
    const int xi1_r = t1 / In, xi1_i = t1 - xi1_r * In;
    const int xsb0 = xi0_r * 128 + (((((xi0_i * 2) >> 4) ^ (xi0_r & 7)) << 4) | ((xi0_i * 2) & 15));
    const int xsb1 = xi1_r * 128 + (((((xi1_i * 2) >> 4) ^ (xi1_r & 7)) << 4) | ((xi1_i * 2) & 15));
    const float* xp0 = x + ((size_t)(b0 + xi0_r) * Tn) * In + xi0_i;
    const float* xp1 = x + ((size_t)(b0 + xi1_r) * Tn) * In + xi1_i;

    // stage x(t=0)
    *(_Float16*)((char*)xs + xsb0) = (_Float16)xp0[0];
    if (has2) *(_Float16*)((char*)xs + xsb1) = (_Float16)xp1[0];

    // per-(wave,lane) weight stream base: frag f = w*80 + s*8 + t
    const char* wpB = (const char*)WPB + (size_t)w * 80 * 1024 + l * 16;
#define BLOAD(s, t) (*(const uint4*)(wpB + (s) * 8192 + (t) * 1024))

    const int r_c  = tid >> 5;         // phase-C row 0..15
    const int c32  = tid & 31;         // phase-C slot
    const int swzC = (r_c & 7);

    uint4 bb[3][8];
    f32x4 acc[8];

    for (int t = 0; t < Tn; t++) {
        // ---- issue next-step x loads + first 3 weight slices (before barrier;
        //      no LDS dependence, stay in flight across it) ----
        float xr0 = 0.f, xr1 = 0.f;
        if (t + 1 < Tn) {
            xr0 = xp0[(size_t)(t + 1) * In];
            if (has2) xr1 = xp1[(size_t)(t + 1) * In];
        }
#pragma unroll
        for (int t8 = 0; t8 < 8; t8++) bb[0][t8] = BLOAD(0, t8);
#pragma unroll
        for (int t8 = 0; t8 < 8; t8++) bb[1][t8] = BLOAD(1, t8);
#pragma unroll
        for (int t8 = 0; t8 < 8; t8++) bb[2][t8] = BLOAD(2, t8);

        __syncthreads();   // hh(t), xs(t) ready

        // ---- phase A: A-fragments + 80 MFMAs over 10 K-slices ----
        half8 af[10];
#pragma unroll
        for (int s = 0; s < 2; s++) {
            const int slot = s * 4 + lq;
            af[s] = *(const half8*)((const char*)xs + lm * 128 + ((slot ^ (lm & 7)) << 4));
        }
#pragma unroll
        for (int s = 0; s < 8; s++) {
            const int slot = s * 4 + lq;
            af[2 + s] = *(const half8*)((const char*)hh + lm * 512 + ((slot ^ (lm & 7)) << 4));
        }
#pragma unroll
        for (int t8 = 0; t8 < 8; t8++) {
            f32x4 a; a[0] = bias[t8]; a[1] = bias[t8]; a[2] = bias[t8]; a[3] = bias[t8];
            acc[t8] = a;
        }
#pragma unroll
        for (int s = 0; s < 10; s++) {
            const half8 a = af[s];
#pragma unroll
            for (int t8 = 0; t8 < 8; t8++)
                acc[t8] = __builtin_amdgcn_mfma_f32_16x16x32_f16(a, u2h(bb[s % 3][t8]), acc[t8], 0, 0, 0);
            if (s < 7) {
#pragma unroll
                for (int t8 = 0; t8 < 8; t8++) bb[s % 3][t8] = BLOAD(s + 3, t8);
            }
        }

        // ---- phase B: tanh + write outs (fp16, swizzled) ----
#pragma unroll
        for (int t8 = 0; t8 < 8; t8++) {
            const int colb = w * 256 + t8 * 32 + lm * 2;   // byte offset of col in row
            const int slot = colb >> 4;
#pragma unroll
            for (int q = 0; q < 4; q++) {
                const int row = lq * 4 + q;
                const float o = tanh_fast(acc[t8][q]);
                *(_Float16*)((char*)outs + row * 2048 + (((slot ^ (row & 7)) << 4) | (colb & 15)))
                    = (_Float16)o;
            }
        }
        __syncthreads();   // outs ready

        // ---- phase B2: gate logits via MFMA over wave's 128-col chunk ----
        f32x4 gacc = {0.f, 0.f, 0.f, 0.f};
#pragma unroll
        for (int s2 = 0; s2 < 4; s2++) {
            const int slot = w * 16 + s2 * 4 + lq;
            const half8 ga = *(const half8*)((const char*)outs + lm * 2048 + ((slot ^ (lm & 7)) << 4));
            gacc = __builtin_amdgcn_mfma_f32_16x16x32_f16(ga, gb[s2], gacc, 0, 0, 0);
        }
        if (lm < 4) {
#pragma unroll
            for (int q = 0; q < 4; q++)
                red[(w * 16 + (lq * 4 + q)) * 4 + lm] = gacc[q];
        }
        __syncthreads();   // red ready

        // ---- phase C: softmax (redundant per thread) + h_new + x store ----
        float lg0 = bg4[0], lg1 = bg4[1], lg2 = bg4[2], lg3 = bg4[3];
#pragma unroll
        for (int w2 = 0; w2 < 8; w2++) {
            const f32x4 v = *(const f32x4*)&red[(w2 * 16 + r_c) * 4];
            lg0 += v[0]; lg1 += v[1]; lg2 += v[2]; lg3 += v[3];
        }
        const float mx = fmaxf(fmaxf(lg0, lg1), fmaxf(lg2, lg3));
        const float e0 = __expf(lg0 - mx), e1 = __expf(lg1 - mx);
        const float e2 = __expf(lg2 - mx), e3 = __expf(lg3 - mx);
        const float inv = __builtin_amdgcn_rcpf(e0 + e1 + e2 + e3);
        half2v wg2[4];
        {
            const float wf[4] = { e0 * inv, e1 * inv, e2 * inv, e3 * inv };
#pragma unroll
            for (int k = 0; k < 4; k++) {
                const _Float16 h = (_Float16)wf[k];
                half2v v2; v2[0] = h; v2[1] = h; wg2[k] = v2;
            }
        }
        half2v hn[4] = {};
#pragma unroll
        for (int k = 0; k < 4; k++) {
            const int slot = k * 32 + c32;
            U4H8 ov;
            ov.h = *(const half8*)((const char*)outs + r_c * 2048 + ((slot ^ swzC) << 4));
#pragma unroll
            for (int p = 0; p < 4; p++)
                hn[p] = hn[p] + ov.h2[p] * wg2[k];     // v_pk_fma_f16
        }
        U4H8 ho;
#pragma unroll
        for (int p = 0; p < 4; p++) ho.h2[p] = hn[p];
        *(uint4*)((char*)hh + r_c * 512 + ((c32 ^ swzC) << 4)) = ho.u;

        if (t + 1 < Tn) {
            *(_Float16*)((char*)xs + xsb0) = (_Float16)xr0;
            if (has2) *(_Float16*)((char*)xs + xsb1) = (_Float16)xr1;
        }
        // loop-top __syncthreads orders hh/xs writes vs next step's reads
    }

    __syncthreads();
    // ---- final FC: 256 threads, one (row, o) each ----
    if (tid < ROWS * On) {
        const int r = tid >> 4, o = tid & 15;
        float s = b_fc[o];
#pragma unroll 4
        for (int j8 = 0; j8 < 32; j8++) {
            const half8 hv = *(const half8*)((const char*)hh + r * 512 + ((j8 ^ (r & 7)) << 4));
#pragma unroll
            for (int jj = 0; jj < 8; jj++)
                s = fmaf((float)hv[jj], W_fc[o * Hn + j8 * 8 + jj], s);
        }
        out[(size_t)(b0 + r) * On + o] = s;
    }
#undef BLOAD
}

extern "C" void kernel_launch(void* const* d_in, const int* in_sizes, int n_in,
                              void* d_out, int out_size, void* d_ws, size_t ws_size,
                              hipStream_t stream) {
    const float* x      = (const float*)d_in[0];
    const float* W_in   = (const float*)d_in[1];
    const float* b_in   = (const float*)d_in[2];
    const float* W_rec  = (const float*)d_in[3];
    const float* b_rec  = (const float*)d_in[4];
    const float* W_gate = (const float*)d_in[5];
    const float* b_gate = (const float*)d_in[6];
    const float* W_fc   = (const float*)d_in[7];
    const float* b_fc   = (const float*)d_in[8];
    float* out = (float*)d_out;

    _Float16* WPB = (_Float16*)d_ws;   // 640 frags * 1024B = 640 KB

    pack_frags<<<640, 64, 0, stream>>>(W_rec, W_in, WPB);
    diru_mfma<<<NBLK, 512, 0, stream>>>(x, WPB, b_in, b_rec,
                                        W_gate, b_gate, W_fc, b_fc, out);
}